// Round 6
// baseline (277.273 us; speedup 1.0000x reference)
//
#include <hip/hip_runtime.h>

// DynamicLinearModel, two-pass version, round 6 (= round-5 resubmit; round 5
// died to an infra failure — "container failed twice", no verdict, same
// signature as round 2 whose identical source later ran clean).
//
// theta_t = a*theta_{t-1} + c_{t-1},  a = sigmoid(G), c = Z@gamma, theta_0 = 0
// out_t   = theta_t + X_t@eta + Z_t@zeta
//
// Invariant established rounds 0-4: ~2.5 TB/s effective demand rate, flat
// across occupancy 20/41/58/73%, shuffle vs DPP reduce, scan vs no-scan.
// Register-load pipelines always collapse (VGPR 32-44 => ~2 loads in flight
// per wave). This round discriminates "per-wave MLP ceiling" (H1) from
// "platform service cap" (H2) via global_load_lds: loads complete into LDS
// with no consuming register, so a wave issues 16 x 1KB loads back-to-back
// (16 KB in flight/wave, 2 blocks/CU x 64 KB outstanding per CU -- 10x the
// Little's-law need for 6.3 TB/s).
//
// LDS layout: linear row-major [128][64] floats per stream (gload_lds writes
// base + lane*16 linearly). Read-side 8-way bank conflict is broken by an
// XOR granule swizzle applied on BOTH sides (rule #21): the per-lane GLOBAL
// source address is pre-swizzled (permutation stays inside each 128 B cache
// line -> coalescing preserved) and the LDS read applies the same XOR.
//
// Pass 1: c[t] = Z[t].gamma -> ws;  b[t] = X[t].eta + Z[t].zeta -> out
// Pass 2: block-local scan over c (64-row geometric lookback, a^63 < 3e-9),
//         out[t] = b[t] + theta_t.

#define WIN     64
#define CHUNK   128      // pass-1 rows per block (64 KB LDS)
#define P2C     256      // pass-2 rows per block
#define FCHUNK  256      // fallback fused kernel
#define RPI     64
#define NITER   ((WIN + FCHUNK) / RPI)

// ---- DPP 16-lane row sum: result in lane 15 of each 16-lane row ----------
template <int N>
__device__ __forceinline__ float rshr_add(float v) {
    const int s = __builtin_amdgcn_update_dpp(
        0, __float_as_int(v), 0x110 | N /*row_shr:N*/, 0xF, 0xF, true);
    return v + __int_as_float(s);
}
__device__ __forceinline__ float rsum16(float v) {
    v = rshr_add<8>(v);
    v = rshr_add<4>(v);
    v = rshr_add<2>(v);
    v = rshr_add<1>(v);
    return v;   // lane 15 of each row holds sum of all 16 lanes
}

// ---- async global->LDS, 16 B per lane (literal size per guide) -----------
__device__ __forceinline__ void gload16(const float* g, float* l) {
    __builtin_amdgcn_global_load_lds(
        (const __attribute__((address_space(1))) void*)g,
        (__attribute__((address_space(3))) void*)l, 16, 0, 0);
}

// ---------------------------------------------------------------------------
// Pass 1: streaming GEMV via global_load_lds staging.
// ---------------------------------------------------------------------------
__global__ __launch_bounds__(256) void dlm_pass1(
    const float* __restrict__ X, const float* __restrict__ Z,
    const float* __restrict__ eta, const float* __restrict__ zeta,
    const float* __restrict__ gam,
    float* __restrict__ c_ws, float* __restrict__ b_out, int T)
{
    const int tid  = threadIdx.x;
    const int lane = tid & 63;
    const int wv   = tid >> 6;        // wave 0..3
    const int sub  = lane & 15;       // granule (16B) index within a row
    const int rsub = lane >> 4;       // row within the 4-row group
    const int s    = (int)blockIdx.x * CHUNK;
    const int Tm1  = T - 1;

    __shared__ __align__(16) float zl[CHUNK * 64];   // 32 KB
    __shared__ __align__(16) float xl[CHUNK * 64];   // 32 KB

    const float4 e4  = ((const float4*)eta)[sub];
    const float4 sz4 = ((const float4*)zeta)[sub];
    const float4 g4  = ((const float4*)gam)[sub];

    // ---- stage: 16 x 1KB gload_lds per wave, all outstanding at once.
    // Wave wv covers local rows [wv*32, wv*32+32). Lane l of wave-load j
    // lands at LDS slot (row rb+l/16, granule l&15); its global source is
    // granule (l&15)^(row&7) of the same row (XOR involution, within-line).
    #pragma unroll
    for (int j = 0; j < 8; ++j) {
        const int rb = wv * 32 + j * 4;            // local row base (uniform)
        const int r  = rb + (lane >> 4);           // local row of this lane
        const int gr = min(s + r, Tm1);            // clamped global row
        const int gs = (lane & 15) ^ (r & 7);      // swizzled source granule
        const size_t o = (size_t)gr * 64 + gs * 4;
        gload16(Z + o, &zl[rb * 64]);
        gload16(X + o, &xl[rb * 64]);
    }
    asm volatile("s_waitcnt vmcnt(0)" ::: "memory");
    __syncthreads();

    // ---- reduce from LDS: 16 lanes per row, DPP row sum, direct stores.
    // LDS slot sub^(ri&7) holds granule sub of row ri (see staging).
    #pragma unroll
    for (int i = 0; i < CHUNK / 64; ++i) {
        #pragma unroll
        for (int u = 0; u < 4; ++u) {
            const int ri = i * 64 + wv * 16 + u * 4 + rsub;   // 0..127
            const int sl = ((sub ^ (ri & 7)) << 2);
            const float4 z = *(const float4*)&zl[ri * 64 + sl];
            const float4 x = *(const float4*)&xl[ri * 64 + sl];
            float cp = z.x*g4.x + z.y*g4.y + z.z*g4.z + z.w*g4.w;
            float bp = x.x*e4.x + x.y*e4.y + x.z*e4.z + x.w*e4.w
                     + z.x*sz4.x + z.y*sz4.y + z.z*sz4.z + z.w*sz4.w;
            cp = rsum16(cp);
            bp = rsum16(bp);
            const int t = s + ri;
            if (sub == 15 && t < T) {      // lanes 15/31/47/63: 4 consecutive rows
                c_ws[t]  = cp;
                b_out[t] = bp;
            }
        }
    }
}

// ---------------------------------------------------------------------------
// Pass 2: per-block scan over materialized c (hot in L2/L3 from pass 1).
// ---------------------------------------------------------------------------
__global__ __launch_bounds__(256) void dlm_pass2(
    const float* __restrict__ c, const float* __restrict__ Gp,
    float* __restrict__ out, int T)
{
    const int tid = threadIdx.x;
    const int s   = (int)blockIdx.x * P2C;
    const int t   = s + tid;

    __shared__ float sc[P2C];
    __shared__ float theta_sh;

    const float g   = *Gp;
    const float a   = 1.0f / (1.0f + expf(-g));
    const float l2a = log2f(a);

    // v_t = c[t-1], v_0 = 0; b read up front (own element only, no hazard)
    const float v = (t >= 1 && t < T) ? c[t - 1] : 0.0f;
    const float b = (t < T) ? out[t] : 0.0f;

    // incoming state: theta_{s-1} = sum_{j=0..WIN-2} a^j * c[s-2-j]
    if (tid < 64) {
        float term = 0.0f;
        const int idx = s - 2 - tid;
        if (tid <= WIN - 2 && idx >= 0)
            term = exp2f((float)tid * l2a) * c[idx];
        #pragma unroll
        for (int off = 1; off <= 32; off <<= 1)
            term += __shfl_xor(term, off, 64);
        if (tid == 0) theta_sh = term;
    }

    sc[tid] = v;
    __syncthreads();
    const float theta_in = theta_sh;

    // inclusive Hillis-Steele scan, ratio a (squares each step)
    float Ad = a;
    for (int d = 1; d < P2C; d <<= 1) {
        const float self = sc[tid];
        const float prev = (tid >= d) ? sc[tid - d] : 0.0f;
        __syncthreads();
        sc[tid] = self + Ad * prev;
        __syncthreads();
        Ad *= Ad;
    }

    const float E = (tid > 0) ? sc[tid - 1] : 0.0f;
    float theta = exp2f((float)tid * l2a) * theta_in + E;
    theta = a * theta + v;
    if (t < T) out[t] = b + theta;
}

// ---------------------------------------------------------------------------
// Fallback: round-1 fused kernel (used only if workspace is too small).
// ---------------------------------------------------------------------------
__global__ __launch_bounds__(256) void dlm_fused(
    const float* __restrict__ X, const float* __restrict__ Z,
    const float* __restrict__ Gp,
    const float* __restrict__ eta, const float* __restrict__ zeta,
    const float* __restrict__ gam,
    float* __restrict__ out, int T)
{
    const int tid  = threadIdx.x;
    const int lane = tid & 63;
    const int wv   = tid >> 6;
    const int sub  = lane & 15;
    const int rsub = lane >> 4;
    const int s    = (int)blockIdx.x * FCHUNK;

    __shared__ float cl[WIN + FCHUNK];
    __shared__ float bl[FCHUNK];
    __shared__ float sc[256];
    __shared__ float theta_sh;

    const float4 e4  = ((const float4*)eta)[sub];
    const float4 sz4 = ((const float4*)zeta)[sub];
    const float4 g4  = ((const float4*)gam)[sub];
    const float4* X4 = (const float4*)X;
    const float4* Z4 = (const float4*)Z;

    const float g   = *Gp;
    const float a   = 1.0f / (1.0f + expf(-g));
    const float l2a = log2f(a);

    for (int i = 0; i < NITER; ++i) {
        const int rb = s - WIN + i * RPI + wv * 16;
        float cp[4], bp[4];
        #pragma unroll
        for (int u = 0; u < 4; ++u) {
            const int r = rb + u * 4 + rsub;
            float4 z = make_float4(0.f, 0.f, 0.f, 0.f);
            float4 x = make_float4(0.f, 0.f, 0.f, 0.f);
            const bool in = (r >= 0) && (r < T);
            if (in)           z = Z4[(size_t)r * 16 + sub];
            if (in && i > 0)  x = X4[(size_t)r * 16 + sub];
            cp[u] = z.x*g4.x + z.y*g4.y + z.z*g4.z + z.w*g4.w;
            bp[u] = x.x*e4.x + x.y*e4.y + x.z*e4.z + x.w*e4.w
                  + z.x*sz4.x + z.y*sz4.y + z.z*sz4.z + z.w*sz4.w;
        }
        #pragma unroll
        for (int u = 0; u < 4; ++u) {
            #pragma unroll
            for (int off = 1; off <= 8; off <<= 1) {
                cp[u] += __shfl_xor(cp[u], off, 64);
                bp[u] += __shfl_xor(bp[u], off, 64);
            }
        }
        if (sub == 0) {
            #pragma unroll
            for (int u = 0; u < 4; ++u) {
                const int r = rb + u * 4 + rsub;
                cl[r - s + WIN] = cp[u];
                if (i > 0) bl[r - s] = bp[u];
            }
        }
    }
    __syncthreads();

    if (tid < 64) {
        float term = 0.0f;
        if (tid <= WIN - 2)
            term = exp2f((float)tid * l2a) * cl[WIN - 2 - tid];
        #pragma unroll
        for (int off = 1; off <= 32; off <<= 1)
            term += __shfl_xor(term, off, 64);
        if (tid == 0) theta_sh = term;
    }

    const int t = s + tid;
    const float v = (t == 0) ? 0.0f : cl[WIN + tid - 1];
    sc[tid] = v;
    __syncthreads();
    const float theta_in = theta_sh;

    float Ad = a;
    for (int d = 1; d < 256; d <<= 1) {
        const float self = sc[tid];
        const float prev = (tid >= d) ? sc[tid - d] : 0.0f;
        __syncthreads();
        sc[tid] = self + Ad * prev;
        __syncthreads();
        Ad *= Ad;
    }

    const float E = (tid > 0) ? sc[tid - 1] : 0.0f;
    float theta = exp2f((float)tid * l2a) * theta_in + E;
    theta = a * theta + v;
    if (t < T) out[t] = bl[tid] + theta;
}

extern "C" void kernel_launch(void* const* d_in, const int* in_sizes, int n_in,
                              void* d_out, int out_size, void* d_ws, size_t ws_size,
                              hipStream_t stream) {
    const float* X     = (const float*)d_in[0];
    const float* Z     = (const float*)d_in[1];
    const float* G     = (const float*)d_in[2];
    const float* eta   = (const float*)d_in[3];
    const float* zeta  = (const float*)d_in[4];
    const float* gamma = (const float*)d_in[5];
    float* out = (float*)d_out;

    const int T = in_sizes[0] / 64;

    if (ws_size >= (size_t)T * sizeof(float)) {
        float* c_ws = (float*)d_ws;
        const int nb1 = (T + CHUNK - 1) / CHUNK;
        const int nb2 = (T + P2C - 1) / P2C;
        dlm_pass1<<<nb1, 256, 0, stream>>>(X, Z, eta, zeta, gamma, c_ws, out, T);
        dlm_pass2<<<nb2, 256, 0, stream>>>(c_ws, G, out, T);
    } else {
        const int nbf = (T + FCHUNK - 1) / FCHUNK;
        dlm_fused<<<nbf, 256, 0, stream>>>(X, Z, G, eta, zeta, gamma, out, T);
    }
}